// Round 7
// baseline (598.381 us; speedup 1.0000x reference)
//
#include <hip/hip_runtime.h>
#include <math.h>

#define NN 500000
#define NB 8192
#define GMAX 16
#define HG_GRID 1536
#define HG_NT ((NN + 63) / 64)

typedef _Float16 f16x8 __attribute__((ext_vector_type(8)));
typedef __fp16 fp16x2 __attribute__((ext_vector_type(2)));
typedef float f32x4 __attribute__((ext_vector_type(4)));

__device__ inline f16x8 cvt8(float4 a, float4 b) {
    union { fp16x2 p[4]; f16x8 r; } u;
    u.p[0] = __builtin_amdgcn_cvt_pkrtz(a.x, a.y);
    u.p[1] = __builtin_amdgcn_cvt_pkrtz(a.z, a.w);
    u.p[2] = __builtin_amdgcn_cvt_pkrtz(b.x, b.y);
    u.p[3] = __builtin_amdgcn_cvt_pkrtz(b.z, b.w);
    return u.r;
}

// ---------------- weight prep: W^T as f16 ----------------
__global__ void prep_w(const float* __restrict__ nw1, const float* __restrict__ nw2,
                       const float* __restrict__ gw1, const float* __restrict__ gw2,
                       const float* __restrict__ qw1, const float* __restrict__ qw2,
                       _Float16* __restrict__ wT1, _Float16* __restrict__ wT2,
                       _Float16* __restrict__ wTg, _Float16* __restrict__ wTq1,
                       _Float16* __restrict__ wTq2, _Float16* __restrict__ g2h) {
    int k = blockIdx.x;   // input dim
    int n = threadIdx.x;  // output dim
    wT1[n * 128 + k]  = (_Float16)nw1[k * 128 + n];
    wT2[n * 128 + k]  = (_Float16)nw2[k * 128 + n];
    wTg[n * 128 + k]  = (_Float16)gw1[k * 128 + n];
    wTq1[n * 128 + k] = (_Float16)qw1[k * 128 + n];
    wTq2[n * 128 + k] = (_Float16)qw2[k * 128 + n];
    if (k == 0) g2h[n] = (_Float16)gw2[n];
}

// ---------------- ques MLP via MFMA (q stored f16) + zero Ppre,s ----------------
__launch_bounds__(512, 4)
__global__ void q_kernel(const float* __restrict__ u,
                         const _Float16* __restrict__ wTq1, const _Float16* __restrict__ wTq2,
                         const float* __restrict__ qb1, const float* __restrict__ qb2,
                         _Float16* __restrict__ q, float* __restrict__ Ppre, float* __restrict__ s) {
    __shared__ __align__(16) _Float16 tbuf[128][136];
    const int tid  = threadIdx.x;
    const int wave = tid >> 6;
    const int lane = tid & 63;
    const int lrow = lane & 15;
    const int quad = lane >> 4;
    const int wr   = wave >> 1;
    const int wc   = wave & 1;
    const int row0 = blockIdx.x * 128;
    const int rbase = wr * 32;

    for (int idx = tid; idx < 128 * 128; idx += 512) Ppre[(size_t)row0 * 128 + idx] = 0.f;
    if (tid < 128) s[row0 + tid] = 0.f;

    f32x4 acc[2][4];
    const f32x4 fz = {0.f, 0.f, 0.f, 0.f};
#pragma unroll
    for (int mi = 0; mi < 2; ++mi)
#pragma unroll
        for (int ci = 0; ci < 4; ++ci) acc[mi][ci] = fz;

#pragma unroll
    for (int ki = 0; ki < 4; ++ki) {
        const int k = ki * 32 + quad * 8;
        f16x8 a[2];
#pragma unroll
        for (int mi = 0; mi < 2; ++mi) {
            int r = row0 + rbase + mi * 16 + lrow;
            const float4* up = (const float4*)(u + (size_t)r * 128 + k);
            a[mi] = cvt8(up[0], up[1]);
        }
        f16x8 b[4];
#pragma unroll
        for (int ci = 0; ci < 4; ++ci)
            b[ci] = *(const f16x8*)(wTq1 + (size_t)(wc * 64 + ci * 16 + lrow) * 128 + k);
#pragma unroll
        for (int mi = 0; mi < 2; ++mi)
#pragma unroll
            for (int ci = 0; ci < 4; ++ci)
                acc[mi][ci] = __builtin_amdgcn_mfma_f32_16x16x32_f16(a[mi], b[ci], acc[mi][ci], 0, 0, 0);
    }
#pragma unroll
    for (int ci = 0; ci < 4; ++ci) {
        int c = wc * 64 + ci * 16 + lrow;
        float bv = qb1[c];
#pragma unroll
        for (int mi = 0; mi < 2; ++mi)
#pragma unroll
            for (int i = 0; i < 4; ++i) {
                int r = rbase + mi * 16 + quad * 4 + i;
                tbuf[r][c] = (_Float16)fmaxf(acc[mi][ci][i] + bv, 0.f);
            }
    }
    __syncthreads();

#pragma unroll
    for (int mi = 0; mi < 2; ++mi)
#pragma unroll
        for (int ci = 0; ci < 4; ++ci) acc[mi][ci] = fz;
#pragma unroll
    for (int ki = 0; ki < 4; ++ki) {
        const int k = ki * 32 + quad * 8;
        f16x8 a[2];
#pragma unroll
        for (int mi = 0; mi < 2; ++mi)
            a[mi] = *(const f16x8*)&tbuf[rbase + mi * 16 + lrow][k];
        f16x8 b[4];
#pragma unroll
        for (int ci = 0; ci < 4; ++ci)
            b[ci] = *(const f16x8*)(wTq2 + (size_t)(wc * 64 + ci * 16 + lrow) * 128 + k);
#pragma unroll
        for (int mi = 0; mi < 2; ++mi)
#pragma unroll
            for (int ci = 0; ci < 4; ++ci)
                acc[mi][ci] = __builtin_amdgcn_mfma_f32_16x16x32_f16(a[mi], b[ci], acc[mi][ci], 0, 0, 0);
    }
#pragma unroll
    for (int ci = 0; ci < 4; ++ci) {
        int c = wc * 64 + ci * 16 + lrow;
        float bv = qb2[c];
#pragma unroll
        for (int mi = 0; mi < 2; ++mi)
#pragma unroll
            for (int i = 0; i < 4; ++i) {
                int r = row0 + rbase + mi * 16 + quad * 4 + i;
                q[(size_t)r * 128 + c] = (_Float16)(acc[mi][ci][i] + bv);
            }
    }
}

// ---------------- fused node-MLP + gate + pool (PERSISTENT, wave-local chain, 1 barrier/tile) ----
// Each wave owns 16 rows and computes ALL 128 cols (acc = 8 x f32x4). M1->M2->M3->gate are then
// wave-local (own-row LDS slices, in-wave lgkmcnt only). The single cross-wave phase is pooling
// (E x t1 over all 64 rows): one __syncthreads per tile; t1/E double-buffered so no 2nd barrier
// (barrier-arrival argument: no wave enters pool(t+1) until all finished pool(t)).
// (256,1): cap 256, no spill (R2-R6 lesson: spill traffic dominated everything).
__launch_bounds__(256, 1)
__global__ void hg_kernel(const float* __restrict__ x, const int* __restrict__ batch,
                          const _Float16* __restrict__ qglob,
                          const _Float16* __restrict__ wT1, const _Float16* __restrict__ wT2,
                          const _Float16* __restrict__ wTg, const _Float16* __restrict__ g2h,
                          const float* __restrict__ nb1, const float* __restrict__ nb2,
                          const float* __restrict__ gb1, const float* __restrict__ gb2,
                          float* __restrict__ Ppre, float* __restrict__ s) {
    __shared__ __align__(16) _Float16 t1buf[2][64][136];   // M1 out (dbuf); pooling B operand
    __shared__ __align__(16) _Float16 Ebuf[2][GMAX][136];  // e by [graph][row] (dbuf)
    __shared__ __align__(16) _Float16 scratch[64][136];    // gin (wave-local rows; single buf ok)

    const int tid  = threadIdx.x;
    const int wave = tid >> 6;      // 0..3; wave owns rows [wave*16, wave*16+16)
    const int lane = tid & 63;
    const int lrow = lane & 15;
    const int quad = lane >> 4;
    const int rbase = wave * 16;
    const int blk  = (int)blockIdx.x;
    const f32x4 fz = {0.f, 0.f, 0.f, 0.f};

    // ---- prologue: first tile's A fragments + batch window ----
    f16x8 a16[4];
    {
        int r = min(blk * 64 + rbase + lrow, NN - 1);
        const float4* xp = (const float4*)(x + (size_t)r * 128 + quad * 8);
#pragma unroll
        for (int ki = 0; ki < 4; ++ki)
            a16[ki] = cvt8(xp[ki * 8], xp[ki * 8 + 1]);
    }
    int bv = batch[min(blk * 64 + lane, NN - 1)];

    int pb = 0;
    for (int t = blk; t < HG_NT; t += HG_GRID, pb ^= 1) {
        const int row0  = t * 64;
        const int rown0 = (t + HG_GRID) * 64;

        // ---- per-wave setup (registers + shuffles; no LDS, no barrier) ----
        const int b_lo = __shfl(bv, 0, 64);
        int rel = bv - b_lo;
#pragma unroll
        for (int off = 32; off >= 1; off >>= 1) rel = max(rel, __shfl_xor(rel, off, 64));
        const int gcnt = min(rel + 1, GMAX);
        int gown[4];
#pragma unroll
        for (int i = 0; i < 4; ++i)
            gown[i] = __shfl(bv, rbase + quad * 4 + i, 64) - b_lo;
        int bv_next = batch[min(rown0 + lane, NN - 1)];

        // zero own-row slice of E[pb] (16 g x 16 r per wave; disjoint by row across waves)
        {
            int g  = lane >> 2;
            int rr = (lane & 3) * 4;
            *(float2*)&Ebuf[pb][g][rbase + rr] = make_float2(0.f, 0.f);
        }

        // ===== M1: t1 = relu(x @ w1 + b1) -> t1buf[pb] own rows =====
        f32x4 acc[8];
#pragma unroll
        for (int ci = 0; ci < 8; ++ci) acc[ci] = fz;
#pragma unroll
        for (int ki = 0; ki < 4; ++ki) {
            const int k = ki * 32 + quad * 8;
            f16x8 b[8];
#pragma unroll
            for (int ci = 0; ci < 8; ++ci)
                b[ci] = *(const f16x8*)(wT1 + (size_t)(ci * 16 + lrow) * 128 + k);
#pragma unroll
            for (int ci = 0; ci < 8; ++ci)
                acc[ci] = __builtin_amdgcn_mfma_f32_16x16x32_f16(a16[ki], b[ci], acc[ci], 0, 0, 0);
        }
#pragma unroll
        for (int ci = 0; ci < 8; ++ci) {
            int c = ci * 16 + lrow;
            float bv1 = nb1[c];
#pragma unroll
            for (int i = 0; i < 4; ++i)
                t1buf[pb][rbase + quad * 4 + i][c] = (_Float16)fmaxf(acc[ci][i] + bv1, 0.f);
        }

        // ---- issue next tile's x loads (own rows; 32 f32 regs; land during M2/M3) ----
        __builtin_amdgcn_sched_barrier(0);
        float4 xraw[4][2];
        {
            int r = min(rown0 + rbase + lrow, NN - 1);
            const float4* xp = (const float4*)(x + (size_t)r * 128 + quad * 8);
#pragma unroll
            for (int ki = 0; ki < 4; ++ki) {
                xraw[ki][0] = xp[ki * 8];
                xraw[ki][1] = xp[ki * 8 + 1];
            }
        }

        // ===== M2: h = t1 @ w2 + b2 ; gin = q[batch]*h -> scratch (all wave-local) =====
#pragma unroll
        for (int ci = 0; ci < 8; ++ci) acc[ci] = fz;
#pragma unroll
        for (int ki = 0; ki < 4; ++ki) {
            const int k = ki * 32 + quad * 8;
            f16x8 a = *(const f16x8*)&t1buf[pb][rbase + lrow][k];
            f16x8 b[8];
#pragma unroll
            for (int ci = 0; ci < 8; ++ci)
                b[ci] = *(const f16x8*)(wT2 + (size_t)(ci * 16 + lrow) * 128 + k);
#pragma unroll
            for (int ci = 0; ci < 8; ++ci)
                acc[ci] = __builtin_amdgcn_mfma_f32_16x16x32_f16(a, b[ci], acc[ci], 0, 0, 0);
        }
        {
            float nb2c[8];
#pragma unroll
            for (int ci = 0; ci < 8; ++ci) nb2c[ci] = nb2[ci * 16 + lrow];
#pragma unroll
            for (int i = 0; i < 4; ++i) {
                const _Float16* qrow = qglob + (size_t)(b_lo + gown[i]) * 128;
                int r = rbase + quad * 4 + i;
#pragma unroll
                for (int ci = 0; ci < 8; ++ci) {
                    int c = ci * 16 + lrow;
                    float h = acc[ci][i] + nb2c[ci];
                    scratch[r][c] = (_Float16)((float)qrow[c] * h);
                }
            }
        }

        // ===== M3: t2 = relu(gin @ gw1 + gb1); gate via in-wave reduce (no LDS/barrier) =====
#pragma unroll
        for (int ci = 0; ci < 8; ++ci) acc[ci] = fz;
#pragma unroll
        for (int ki = 0; ki < 4; ++ki) {
            const int k = ki * 32 + quad * 8;
            f16x8 a = *(const f16x8*)&scratch[rbase + lrow][k];
            f16x8 b[8];
#pragma unroll
            for (int ci = 0; ci < 8; ++ci)
                b[ci] = *(const f16x8*)(wTg + (size_t)(ci * 16 + lrow) * 128 + k);
#pragma unroll
            for (int ci = 0; ci < 8; ++ci)
                acc[ci] = __builtin_amdgcn_mfma_f32_16x16x32_f16(a, b[ci], acc[ci], 0, 0, 0);
        }
        {
            float p[4] = {0.f, 0.f, 0.f, 0.f};
#pragma unroll
            for (int ci = 0; ci < 8; ++ci) {
                int c = ci * 16 + lrow;
                float b1 = gb1[c];
                float w = (float)g2h[c];
#pragma unroll
                for (int i = 0; i < 4; ++i)
                    p[i] = fmaf(fmaxf(acc[ci][i] + b1, 0.f), w, p[i]);
            }
#pragma unroll
            for (int off = 1; off <= 8; off <<= 1)
#pragma unroll
                for (int i = 0; i < 4; ++i)
                    p[i] += __shfl_xor(p[i], off, 64);
            const float gb2v = gb2[0];
            if (lrow == 0) {
#pragma unroll
                for (int i = 0; i < 4; ++i) {
                    int r = rbase + quad * 4 + i;
                    bool valid = (row0 + r) < NN;
                    float e = valid ? __expf(p[i] + gb2v) : 0.f;
                    int g = gown[i];
                    if (g < GMAX) {
                        Ebuf[pb][g][r] = (_Float16)e;
                    } else if (valid) {  // pathological >16 graphs in window
                        atomicAdd(&s[b_lo + g], e);
                        for (int c = 0; c < 128; ++c)
                            atomicAdd(&Ppre[(size_t)(b_lo + g) * 128 + c],
                                      e * (float)t1buf[pb][r][c]);
                    }
                }
            }
        }

        // convert next tile's x (loads issued before M2 -> long since landed)
#pragma unroll
        for (int ki = 0; ki < 4; ++ki)
            a16[ki] = cvt8(xraw[ki][0], xraw[ki][1]);
        bv = bv_next;

        __syncthreads();  // the ONE barrier: E[pb] + t1buf[pb] visible to all waves

        // ===== pooling: Ppre += E(16g x 64r) @ t1(64r x 128c); wave covers 32 cols =====
        f16x8 aE[2];
#pragma unroll
        for (int ki2 = 0; ki2 < 2; ++ki2)
            aE[ki2] = *(const f16x8*)&Ebuf[pb][lrow][ki2 * 32 + quad * 8];
        f32x4 pacc[2] = {fz, fz};
#pragma unroll
        for (int ci2 = 0; ci2 < 2; ++ci2) {
            int col = wave * 32 + ci2 * 16 + lrow;
#pragma unroll
            for (int ki2 = 0; ki2 < 2; ++ki2) {
                f16x8 bh;
#pragma unroll
                for (int j = 0; j < 8; ++j) bh[j] = t1buf[pb][ki2 * 32 + quad * 8 + j][col];
                pacc[ci2] = __builtin_amdgcn_mfma_f32_16x16x32_f16(aE[ki2], bh, pacc[ci2], 0, 0, 0);
            }
        }
#pragma unroll
        for (int ci2 = 0; ci2 < 2; ++ci2)
#pragma unroll
            for (int i = 0; i < 4; ++i) {
                int g = quad * 4 + i;
                if (g < gcnt)
                    atomicAdd(&Ppre[(size_t)(b_lo + g) * 128 + wave * 32 + ci2 * 16 + lrow],
                              pacc[ci2][i]);
            }
        // s[g] = sum_r E[g][r] (wave 0; scalar reduce, avoids col-overrun tricks)
        if (wave == 0) {
            float sv = 0.f;
#pragma unroll
            for (int j = 0; j < 16; ++j) sv += (float)Ebuf[pb][lrow][quad * 16 + j];
            sv += __shfl_xor(sv, 16, 64);
            sv += __shfl_xor(sv, 32, 64);
            if (quad == 0 && lrow < gcnt) atomicAdd(&s[b_lo + lrow], sv);
        }
        // no trailing barrier: dbuf + barrier-arrival argument make next-tile writes safe
    }
}

// ---------------- finalize: out = (Ppre @ w2 + s*b2) / (s + eps) ----------------
__launch_bounds__(512, 4)
__global__ void fin_kernel(const float* __restrict__ Ppre, const float* __restrict__ s,
                           const _Float16* __restrict__ wT2, const float* __restrict__ nb2,
                           float* __restrict__ out) {
    const int tid  = threadIdx.x;
    const int wave = tid >> 6;
    const int lane = tid & 63;
    const int lrow = lane & 15;
    const int quad = lane >> 4;
    const int wr   = wave >> 1;
    const int wc   = wave & 1;
    const int row0 = blockIdx.x * 128;
    const int rbase = wr * 32;

    f32x4 acc[2][4];
    const f32x4 fz = {0.f, 0.f, 0.f, 0.f};
#pragma unroll
    for (int mi = 0; mi < 2; ++mi)
#pragma unroll
        for (int ci = 0; ci < 4; ++ci) acc[mi][ci] = fz;
#pragma unroll
    for (int ki = 0; ki < 4; ++ki) {
        const int k = ki * 32 + quad * 8;
        f16x8 a[2];
#pragma unroll
        for (int mi = 0; mi < 2; ++mi) {
            int r = row0 + rbase + mi * 16 + lrow;
            const float4* pp = (const float4*)(Ppre + (size_t)r * 128 + k);
            a[mi] = cvt8(pp[0], pp[1]);
        }
        f16x8 b[4];
#pragma unroll
        for (int ci = 0; ci < 4; ++ci)
            b[ci] = *(const f16x8*)(wT2 + (size_t)(wc * 64 + ci * 16 + lrow) * 128 + k);
#pragma unroll
        for (int mi = 0; mi < 2; ++mi)
#pragma unroll
            for (int ci = 0; ci < 4; ++ci)
                acc[mi][ci] = __builtin_amdgcn_mfma_f32_16x16x32_f16(a[mi], b[ci], acc[mi][ci], 0, 0, 0);
    }
    float sv[2][4], rinv[2][4];
#pragma unroll
    for (int mi = 0; mi < 2; ++mi)
#pragma unroll
        for (int i = 0; i < 4; ++i) {
            int r = row0 + rbase + mi * 16 + quad * 4 + i;
            sv[mi][i] = s[r];
            rinv[mi][i] = 1.f / (sv[mi][i] + 1e-16f);
        }
#pragma unroll
    for (int ci = 0; ci < 4; ++ci) {
        int c = wc * 64 + ci * 16 + lrow;
        float bv = nb2[c];
#pragma unroll
        for (int mi = 0; mi < 2; ++mi)
#pragma unroll
            for (int i = 0; i < 4; ++i) {
                int r = row0 + rbase + mi * 16 + quad * 4 + i;
                out[(size_t)r * 128 + c] = (acc[mi][ci][i] + sv[mi][i] * bv) * rinv[mi][i];
            }
    }
}

extern "C" void kernel_launch(void* const* d_in, const int* in_sizes, int n_in,
                              void* d_out, int out_size, void* d_ws, size_t ws_size,
                              hipStream_t stream) {
    const float* x    = (const float*)d_in[0];
    const float* u    = (const float*)d_in[1];
    const int* batch  = (const int*)d_in[2];
    const float* gw1  = (const float*)d_in[4];
    const float* gb1  = (const float*)d_in[5];
    const float* gw2  = (const float*)d_in[6];
    const float* gb2  = (const float*)d_in[7];
    const float* nw1  = (const float*)d_in[8];
    const float* nb1  = (const float*)d_in[9];
    const float* nw2  = (const float*)d_in[10];
    const float* nb2  = (const float*)d_in[11];
    const float* qw1  = (const float*)d_in[12];
    const float* qb1  = (const float*)d_in[13];
    const float* qw2  = (const float*)d_in[14];
    const float* qb2  = (const float*)d_in[15];

    char* ws = (char*)d_ws;
    _Float16* q   = (_Float16*)ws;                       // 2 MB
    float* Ppre   = (float*)(ws + 2097152);              // 4 MB
    float* s      = (float*)(ws + 6291456);              // 32 KB
    _Float16* wT1 = (_Float16*)(ws + 6324224);           // 5 x 32 KB + g2h
    _Float16* wT2  = wT1 + 16384;
    _Float16* wTg  = wT2 + 16384;
    _Float16* wTq1 = wTg + 16384;
    _Float16* wTq2 = wTq1 + 16384;
    _Float16* g2h  = wTq2 + 16384;
    float* out = (float*)d_out;

    hipLaunchKernelGGL(prep_w, dim3(128), dim3(128), 0, stream,
                       nw1, nw2, gw1, gw2, qw1, qw2, wT1, wT2, wTg, wTq1, wTq2, g2h);
    hipLaunchKernelGGL(q_kernel, dim3(NB / 128), dim3(512), 0, stream,
                       u, wTq1, wTq2, qb1, qb2, q, Ppre, s);
    hipLaunchKernelGGL(hg_kernel, dim3(HG_GRID), dim3(256), 0, stream,
                       x, batch, q, wT1, wT2, wTg, g2h, nb1, nb2, gb1, gb2, Ppre, s);
    hipLaunchKernelGGL(fin_kernel, dim3(NB / 128), dim3(512), 0, stream,
                       Ppre, s, wT2, nb2, out);
}

// Round 8
// 563.262 us; speedup vs baseline: 1.0623x; 1.0623x over previous
//
#include <hip/hip_runtime.h>
#include <math.h>

#define NN 500000
#define NB 8192
#define GMAX 16
#define TROWS 128
#define HG_GRID 512
#define HG_NT ((NN + TROWS - 1) / TROWS)

typedef _Float16 f16x8 __attribute__((ext_vector_type(8)));
typedef __fp16 fp16x2 __attribute__((ext_vector_type(2)));
typedef float f32x4 __attribute__((ext_vector_type(4)));

__device__ inline f16x8 cvt8(float4 a, float4 b) {
    union { fp16x2 p[4]; f16x8 r; } u;
    u.p[0] = __builtin_amdgcn_cvt_pkrtz(a.x, a.y);
    u.p[1] = __builtin_amdgcn_cvt_pkrtz(a.z, a.w);
    u.p[2] = __builtin_amdgcn_cvt_pkrtz(b.x, b.y);
    u.p[3] = __builtin_amdgcn_cvt_pkrtz(b.z, b.w);
    return u.r;
}

// ---------------- weight prep: W^T as f16 ----------------
__global__ void prep_w(const float* __restrict__ nw1, const float* __restrict__ nw2,
                       const float* __restrict__ gw1, const float* __restrict__ gw2,
                       const float* __restrict__ qw1, const float* __restrict__ qw2,
                       _Float16* __restrict__ wT1, _Float16* __restrict__ wT2,
                       _Float16* __restrict__ wTg, _Float16* __restrict__ wTq1,
                       _Float16* __restrict__ wTq2, _Float16* __restrict__ g2h) {
    int k = blockIdx.x;   // input dim
    int n = threadIdx.x;  // output dim
    wT1[n * 128 + k]  = (_Float16)nw1[k * 128 + n];
    wT2[n * 128 + k]  = (_Float16)nw2[k * 128 + n];
    wTg[n * 128 + k]  = (_Float16)gw1[k * 128 + n];
    wTq1[n * 128 + k] = (_Float16)qw1[k * 128 + n];
    wTq2[n * 128 + k] = (_Float16)qw2[k * 128 + n];
    if (k == 0) g2h[n] = (_Float16)gw2[n];
}

// ---------------- ques MLP via MFMA (q stored f16) + zero Ppre,s (128 blocks x 64 rows) ----
__launch_bounds__(256, 2)
__global__ void q_kernel(const float* __restrict__ u,
                         const _Float16* __restrict__ wTq1, const _Float16* __restrict__ wTq2,
                         const float* __restrict__ qb1, const float* __restrict__ qb2,
                         _Float16* __restrict__ q, float* __restrict__ Ppre, float* __restrict__ s) {
    __shared__ __align__(16) _Float16 tbuf[64][136];
    const int tid  = threadIdx.x;
    const int wave = tid >> 6;
    const int lane = tid & 63;
    const int lrow = lane & 15;
    const int quad = lane >> 4;
    const int wr   = wave >> 1;
    const int wc   = wave & 1;
    const int row0 = (int)blockIdx.x * 64;
    const int rbase = wr * 32;

    for (int idx = tid; idx < 64 * 128; idx += 256) Ppre[(size_t)row0 * 128 + idx] = 0.f;
    if (tid < 64) s[row0 + tid] = 0.f;

    f32x4 acc[2][4];
    const f32x4 fz = {0.f, 0.f, 0.f, 0.f};
#pragma unroll
    for (int mi = 0; mi < 2; ++mi)
#pragma unroll
        for (int ci = 0; ci < 4; ++ci) acc[mi][ci] = fz;

#pragma unroll
    for (int ki = 0; ki < 4; ++ki) {
        const int k = ki * 32 + quad * 8;
        f16x8 a[2];
#pragma unroll
        for (int mi = 0; mi < 2; ++mi) {
            int r = row0 + rbase + mi * 16 + lrow;
            const float4* up = (const float4*)(u + (size_t)r * 128 + k);
            a[mi] = cvt8(up[0], up[1]);
        }
        f16x8 b[4];
#pragma unroll
        for (int ci = 0; ci < 4; ++ci)
            b[ci] = *(const f16x8*)(wTq1 + (size_t)(wc * 64 + ci * 16 + lrow) * 128 + k);
#pragma unroll
        for (int mi = 0; mi < 2; ++mi)
#pragma unroll
            for (int ci = 0; ci < 4; ++ci)
                acc[mi][ci] = __builtin_amdgcn_mfma_f32_16x16x32_f16(a[mi], b[ci], acc[mi][ci], 0, 0, 0);
    }
#pragma unroll
    for (int ci = 0; ci < 4; ++ci) {
        int c = wc * 64 + ci * 16 + lrow;
        float bv = qb1[c];
#pragma unroll
        for (int mi = 0; mi < 2; ++mi)
#pragma unroll
            for (int i = 0; i < 4; ++i) {
                int r = rbase + mi * 16 + quad * 4 + i;
                tbuf[r][c] = (_Float16)fmaxf(acc[mi][ci][i] + bv, 0.f);
            }
    }
    __syncthreads();

#pragma unroll
    for (int mi = 0; mi < 2; ++mi)
#pragma unroll
        for (int ci = 0; ci < 4; ++ci) acc[mi][ci] = fz;
#pragma unroll
    for (int ki = 0; ki < 4; ++ki) {
        const int k = ki * 32 + quad * 8;
        f16x8 a[2];
#pragma unroll
        for (int mi = 0; mi < 2; ++mi)
            a[mi] = *(const f16x8*)&tbuf[rbase + mi * 16 + lrow][k];
        f16x8 b[4];
#pragma unroll
        for (int ci = 0; ci < 4; ++ci)
            b[ci] = *(const f16x8*)(wTq2 + (size_t)(wc * 64 + ci * 16 + lrow) * 128 + k);
#pragma unroll
        for (int mi = 0; mi < 2; ++mi)
#pragma unroll
            for (int ci = 0; ci < 4; ++ci)
                acc[mi][ci] = __builtin_amdgcn_mfma_f32_16x16x32_f16(a[mi], b[ci], acc[mi][ci], 0, 0, 0);
    }
#pragma unroll
    for (int ci = 0; ci < 4; ++ci) {
        int c = wc * 64 + ci * 16 + lrow;
        float bv = qb2[c];
#pragma unroll
        for (int mi = 0; mi < 2; ++mi)
#pragma unroll
            for (int i = 0; i < 4; ++i) {
                int r = row0 + rbase + mi * 16 + quad * 4 + i;
                q[(size_t)r * 128 + c] = (_Float16)(acc[mi][ci][i] + bv);
            }
    }
}

// ---------------- fused node-MLP + gate + pool: 128-ROW TILES (amortize per-tile stall) ------
// R0/R6/R7 all land at 275-307us despite wildly different structures (5-bar vs 1-bar,
// non/persistent, prefetch) -> per-tile stall is ~constant, every pipe <17% busy. Lever:
// HALVE the tile count. 4 waves x 32 rows, each wave ALL 128 cols (wave-local M1->M2->M3->gate,
// acc[2][8]); 2 barriers/tile. LDS ~73KB -> 2 blocks/CU; (256,1) cap 256, demand ~200 -> no
// spill. Grid 512 = resident set exactly.
__launch_bounds__(256, 1)
__global__ void hg_kernel(const float* __restrict__ x, const int* __restrict__ batch,
                          const _Float16* __restrict__ qglob,
                          const _Float16* __restrict__ wT1, const _Float16* __restrict__ wT2,
                          const _Float16* __restrict__ wTg, const _Float16* __restrict__ g2h,
                          const float* __restrict__ nb1, const float* __restrict__ nb2,
                          const float* __restrict__ gb1, const float* __restrict__ gb2,
                          float* __restrict__ Ppre, float* __restrict__ s) {
    __shared__ __align__(16) _Float16 t1buf[TROWS][136];    // M1 out; M2 in; pooling B
    __shared__ __align__(16) _Float16 scratch[TROWS][136];  // gin (wave-local rows)
    __shared__ __align__(16) _Float16 Ebuf[GMAX][136];      // e by [graph][row]
    __shared__ int batch_t[TROWS];

    const int tid  = threadIdx.x;
    const int wave = tid >> 6;      // 0..3; wave owns rows [wave*32, wave*32+32)
    const int lane = tid & 63;
    const int lrow = lane & 15;
    const int quad = lane >> 4;
    const int rbase = wave * 32;
    const int blk  = (int)blockIdx.x;
    const f32x4 fz = {0.f, 0.f, 0.f, 0.f};

    // ---- prologue: first tile's A fragments + batch window ----
    f16x8 a16[4][2];
    {
        const int r0 = blk * TROWS;
#pragma unroll
        for (int ki = 0; ki < 4; ++ki)
#pragma unroll
            for (int mi = 0; mi < 2; ++mi) {
                int r = min(r0 + rbase + mi * 16 + lrow, NN - 1);
                const float4* xp = (const float4*)(x + (size_t)r * 128 + ki * 32 + quad * 8);
                a16[ki][mi] = cvt8(xp[0], xp[1]);
            }
    }
    int bvr = batch[min(blk * TROWS + rbase + (lane & 31), NN - 1)];

    for (int t = blk; t < HG_NT; t += HG_GRID) {
        const int row0  = t * TROWS;
        const int rown0 = (t + HG_GRID) * TROWS;

        if (lane < 32) batch_t[rbase + lane] = bvr;
        __syncthreads();  // bar A: batch_t visible; prev pooling done -> t1/E reusable
        const int b_lo = batch_t[0];
        const int gcnt = min(batch_t[TROWS - 1] - b_lo + 1, GMAX);  // batch is sorted
        // prefetch next tile's batch window
        bvr = batch[min(rown0 + rbase + (lane & 31), NN - 1)];

        int gown[2][4];
#pragma unroll
        for (int mi = 0; mi < 2; ++mi)
#pragma unroll
            for (int i = 0; i < 4; ++i)
                gown[mi][i] = batch_t[rbase + mi * 16 + quad * 4 + i] - b_lo;

        // zero own-row slice of E (16 g x 32 r per wave)
        {
            int g = lane >> 2;
            int r0e = rbase + (lane & 3) * 8;
            *(float4*)&Ebuf[g][r0e] = make_float4(0.f, 0.f, 0.f, 0.f);
        }

        // ===== M1: t1 = relu(x @ w1 + b1) -> t1buf own rows (all 128 cols) =====
        f32x4 acc[2][8];
#pragma unroll
        for (int mi = 0; mi < 2; ++mi)
#pragma unroll
            for (int ci = 0; ci < 8; ++ci) acc[mi][ci] = fz;
#pragma unroll
        for (int ki = 0; ki < 4; ++ki) {
            const int k = ki * 32 + quad * 8;
            f16x8 b[8];
#pragma unroll
            for (int ci = 0; ci < 8; ++ci)
                b[ci] = *(const f16x8*)(wT1 + (size_t)(ci * 16 + lrow) * 128 + k);
#pragma unroll
            for (int mi = 0; mi < 2; ++mi)
#pragma unroll
                for (int ci = 0; ci < 8; ++ci)
                    acc[mi][ci] = __builtin_amdgcn_mfma_f32_16x16x32_f16(a16[ki][mi], b[ci], acc[mi][ci], 0, 0, 0);
        }
#pragma unroll
        for (int ci = 0; ci < 8; ++ci) {
            int c = ci * 16 + lrow;
            float bv1 = nb1[c];
#pragma unroll
            for (int mi = 0; mi < 2; ++mi)
#pragma unroll
                for (int i = 0; i < 4; ++i)
                    t1buf[rbase + mi * 16 + quad * 4 + i][c] = (_Float16)fmaxf(acc[mi][ci][i] + bv1, 0.f);
        }

        // ---- issue chunk A of next tile's x (ki=0,1; 32 f32 regs) ----
        __builtin_amdgcn_sched_barrier(0);
        float4 xrawA[2][2][2];
#pragma unroll
        for (int ki = 0; ki < 2; ++ki)
#pragma unroll
            for (int mi = 0; mi < 2; ++mi) {
                int r = min(rown0 + rbase + mi * 16 + lrow, NN - 1);
                const float4* xp = (const float4*)(x + (size_t)r * 128 + ki * 32 + quad * 8);
                xrawA[ki][mi][0] = xp[0];
                xrawA[ki][mi][1] = xp[1];
            }

        // ===== M2: h = t1 @ w2 + b2 ; gin = q[batch]*h -> scratch (wave-local) =====
#pragma unroll
        for (int mi = 0; mi < 2; ++mi)
#pragma unroll
            for (int ci = 0; ci < 8; ++ci) acc[mi][ci] = fz;
#pragma unroll
        for (int ki = 0; ki < 4; ++ki) {
            const int k = ki * 32 + quad * 8;
            f16x8 a[2];
#pragma unroll
            for (int mi = 0; mi < 2; ++mi)
                a[mi] = *(const f16x8*)&t1buf[rbase + mi * 16 + lrow][k];
            f16x8 b[8];
#pragma unroll
            for (int ci = 0; ci < 8; ++ci)
                b[ci] = *(const f16x8*)(wT2 + (size_t)(ci * 16 + lrow) * 128 + k);
#pragma unroll
            for (int mi = 0; mi < 2; ++mi)
#pragma unroll
                for (int ci = 0; ci < 8; ++ci)
                    acc[mi][ci] = __builtin_amdgcn_mfma_f32_16x16x32_f16(a[mi], b[ci], acc[mi][ci], 0, 0, 0);
        }
#pragma unroll
        for (int mi = 0; mi < 2; ++mi)
#pragma unroll
            for (int i = 0; i < 4; ++i) {
                int r = rbase + mi * 16 + quad * 4 + i;
                const _Float16* qrow = qglob + (size_t)(b_lo + gown[mi][i]) * 128;
#pragma unroll
                for (int ci = 0; ci < 8; ++ci) {
                    int c = ci * 16 + lrow;
                    float h = acc[mi][ci][i] + nb2[c];
                    scratch[r][c] = (_Float16)((float)qrow[c] * h);
                }
            }

        // convert chunk A -> a16[0..1] (loads covered by M2)
#pragma unroll
        for (int ki = 0; ki < 2; ++ki)
#pragma unroll
            for (int mi = 0; mi < 2; ++mi)
                a16[ki][mi] = cvt8(xrawA[ki][mi][0], xrawA[ki][mi][1]);

        // ===== M3: t2 = relu(gin @ gw1 + gb1); gate via in-wave reduce =====
#pragma unroll
        for (int mi = 0; mi < 2; ++mi)
#pragma unroll
            for (int ci = 0; ci < 8; ++ci) acc[mi][ci] = fz;
#pragma unroll
        for (int ki = 0; ki < 4; ++ki) {
            const int k = ki * 32 + quad * 8;
            f16x8 a[2];
#pragma unroll
            for (int mi = 0; mi < 2; ++mi)
                a[mi] = *(const f16x8*)&scratch[rbase + mi * 16 + lrow][k];
            f16x8 b[8];
#pragma unroll
            for (int ci = 0; ci < 8; ++ci)
                b[ci] = *(const f16x8*)(wTg + (size_t)(ci * 16 + lrow) * 128 + k);
#pragma unroll
            for (int mi = 0; mi < 2; ++mi)
#pragma unroll
                for (int ci = 0; ci < 8; ++ci)
                    acc[mi][ci] = __builtin_amdgcn_mfma_f32_16x16x32_f16(a[mi], b[ci], acc[mi][ci], 0, 0, 0);
        }

        // ---- issue chunk B of next tile's x (ki=2,3) ----
        __builtin_amdgcn_sched_barrier(0);
        float4 xrawB[2][2][2];
#pragma unroll
        for (int ki = 0; ki < 2; ++ki)
#pragma unroll
            for (int mi = 0; mi < 2; ++mi) {
                int r = min(rown0 + rbase + mi * 16 + lrow, NN - 1);
                const float4* xp = (const float4*)(x + (size_t)r * 128 + (ki + 2) * 32 + quad * 8);
                xrawB[ki][mi][0] = xp[0];
                xrawB[ki][mi][1] = xp[1];
            }

        {
            float p[2][4] = {{0.f, 0.f, 0.f, 0.f}, {0.f, 0.f, 0.f, 0.f}};
#pragma unroll
            for (int ci = 0; ci < 8; ++ci) {
                int c = ci * 16 + lrow;
                float b1 = gb1[c];
                float w = (float)g2h[c];
#pragma unroll
                for (int mi = 0; mi < 2; ++mi)
#pragma unroll
                    for (int i = 0; i < 4; ++i)
                        p[mi][i] = fmaf(fmaxf(acc[mi][ci][i] + b1, 0.f), w, p[mi][i]);
            }
#pragma unroll
            for (int off = 1; off <= 8; off <<= 1)
#pragma unroll
                for (int mi = 0; mi < 2; ++mi)
#pragma unroll
                    for (int i = 0; i < 4; ++i)
                        p[mi][i] += __shfl_xor(p[mi][i], off, 64);
            const float gb2v = gb2[0];
            if (lrow == 0) {
#pragma unroll
                for (int mi = 0; mi < 2; ++mi)
#pragma unroll
                    for (int i = 0; i < 4; ++i) {
                        int r = rbase + mi * 16 + quad * 4 + i;
                        bool valid = (row0 + r) < NN;
                        float e = valid ? __expf(p[mi][i] + gb2v) : 0.f;
                        int g = gown[mi][i];
                        if (g < GMAX) {
                            Ebuf[g][r] = (_Float16)e;
                        } else if (valid) {  // pathological >16 graphs in window
                            atomicAdd(&s[b_lo + g], e);
                            for (int c = 0; c < 128; ++c)
                                atomicAdd(&Ppre[(size_t)(b_lo + g) * 128 + c],
                                          e * (float)t1buf[r][c]);
                        }
                    }
            }
        }
        __syncthreads();  // bar B: E + t1 visible to all waves

        // ===== pooling: Ppre += E(16g x 128r) @ t1(128r x 128c); wave covers 32 cols =====
        f16x8 aE[4];
#pragma unroll
        for (int ki2 = 0; ki2 < 4; ++ki2)
            aE[ki2] = *(const f16x8*)&Ebuf[lrow][ki2 * 32 + quad * 8];
        f32x4 pacc[2] = {fz, fz};
#pragma unroll
        for (int ci2 = 0; ci2 < 2; ++ci2) {
            int col = wave * 32 + ci2 * 16 + lrow;
#pragma unroll
            for (int ki2 = 0; ki2 < 4; ++ki2) {
                f16x8 bh;
#pragma unroll
                for (int j = 0; j < 8; ++j) bh[j] = t1buf[ki2 * 32 + quad * 8 + j][col];
                pacc[ci2] = __builtin_amdgcn_mfma_f32_16x16x32_f16(aE[ki2], bh, pacc[ci2], 0, 0, 0);
            }
        }
#pragma unroll
        for (int ci2 = 0; ci2 < 2; ++ci2)
#pragma unroll
            for (int i = 0; i < 4; ++i) {
                int g = quad * 4 + i;
                if (g < gcnt)
                    atomicAdd(&Ppre[(size_t)(b_lo + g) * 128 + wave * 32 + ci2 * 16 + lrow],
                              pacc[ci2][i]);
            }
        // s[g] += sum_r E[g][r] (wave 0)
        if (wave == 0) {
            float sv = 0.f;
#pragma unroll
            for (int j = 0; j < 32; ++j) sv += (float)Ebuf[lrow][quad * 32 + j];
            sv += __shfl_xor(sv, 16, 64);
            sv += __shfl_xor(sv, 32, 64);
            if (quad == 0 && lrow < gcnt) atomicAdd(&s[b_lo + lrow], sv);
        }

        // convert chunk B -> a16[2..3]
#pragma unroll
        for (int ki = 0; ki < 2; ++ki)
#pragma unroll
            for (int mi = 0; mi < 2; ++mi)
                a16[ki + 2][mi] = cvt8(xrawB[ki][mi][0], xrawB[ki][mi][1]);
    }
}

// ---------------- finalize: out = (Ppre @ w2 + s*b2) / (s + eps)  (256 blocks x 32 rows) ----
__launch_bounds__(256, 2)
__global__ void fin_kernel(const float* __restrict__ Ppre, const float* __restrict__ s,
                           const _Float16* __restrict__ wT2, const float* __restrict__ nb2,
                           float* __restrict__ out) {
    const int tid  = threadIdx.x;
    const int wave = tid >> 6;
    const int lane = tid & 63;
    const int lrow = lane & 15;
    const int quad = lane >> 4;
    const int wr   = wave >> 1;
    const int wc   = wave & 1;
    const int row0 = (int)blockIdx.x * 32;
    const int rbase = wr * 16;

    f32x4 acc[4];
    const f32x4 fz = {0.f, 0.f, 0.f, 0.f};
#pragma unroll
    for (int ci = 0; ci < 4; ++ci) acc[ci] = fz;
#pragma unroll
    for (int ki = 0; ki < 4; ++ki) {
        const int k = ki * 32 + quad * 8;
        int r = row0 + rbase + lrow;
        const float4* pp = (const float4*)(Ppre + (size_t)r * 128 + k);
        f16x8 a = cvt8(pp[0], pp[1]);
        f16x8 b[4];
#pragma unroll
        for (int ci = 0; ci < 4; ++ci)
            b[ci] = *(const f16x8*)(wT2 + (size_t)(wc * 64 + ci * 16 + lrow) * 128 + k);
#pragma unroll
        for (int ci = 0; ci < 4; ++ci)
            acc[ci] = __builtin_amdgcn_mfma_f32_16x16x32_f16(a, b[ci], acc[ci], 0, 0, 0);
    }
    float sv[4], rinv[4];
#pragma unroll
    for (int i = 0; i < 4; ++i) {
        int r = row0 + rbase + quad * 4 + i;
        sv[i] = s[r];
        rinv[i] = 1.f / (sv[i] + 1e-16f);
    }
#pragma unroll
    for (int ci = 0; ci < 4; ++ci) {
        int c = wc * 64 + ci * 16 + lrow;
        float bv = nb2[c];
#pragma unroll
        for (int i = 0; i < 4; ++i) {
            int r = row0 + rbase + quad * 4 + i;
            out[(size_t)r * 128 + c] = (acc[ci][i] + sv[i] * bv) * rinv[i];
        }
    }
}

extern "C" void kernel_launch(void* const* d_in, const int* in_sizes, int n_in,
                              void* d_out, int out_size, void* d_ws, size_t ws_size,
                              hipStream_t stream) {
    const float* x    = (const float*)d_in[0];
    const float* u    = (const float*)d_in[1];
    const int* batch  = (const int*)d_in[2];
    const float* gw1  = (const float*)d_in[4];
    const float* gb1  = (const float*)d_in[5];
    const float* gw2  = (const float*)d_in[6];
    const float* gb2  = (const float*)d_in[7];
    const float* nw1  = (const float*)d_in[8];
    const float* nb1  = (const float*)d_in[9];
    const float* nw2  = (const float*)d_in[10];
    const float* nb2  = (const float*)d_in[11];
    const float* qw1  = (const float*)d_in[12];
    const float* qb1  = (const float*)d_in[13];
    const float* qw2  = (const float*)d_in[14];
    const float* qb2  = (const float*)d_in[15];

    char* ws = (char*)d_ws;
    _Float16* q   = (_Float16*)ws;                       // 2 MB
    float* Ppre   = (float*)(ws + 2097152);              // 4 MB
    float* s      = (float*)(ws + 6291456);              // 32 KB
    _Float16* wT1 = (_Float16*)(ws + 6324224);           // 5 x 32 KB + g2h
    _Float16* wT2  = wT1 + 16384;
    _Float16* wTg  = wT2 + 16384;
    _Float16* wTq1 = wTg + 16384;
    _Float16* wTq2 = wTq1 + 16384;
    _Float16* g2h  = wTq2 + 16384;
    float* out = (float*)d_out;

    hipLaunchKernelGGL(prep_w, dim3(128), dim3(128), 0, stream,
                       nw1, nw2, gw1, gw2, qw1, qw2, wT1, wT2, wTg, wTq1, wTq2, g2h);
    hipLaunchKernelGGL(q_kernel, dim3(NB / 64), dim3(256), 0, stream,
                       u, wTq1, wTq2, qb1, qb2, q, Ppre, s);
    hipLaunchKernelGGL(hg_kernel, dim3(HG_GRID), dim3(256), 0, stream,
                       x, batch, q, wT1, wT2, wTg, g2h, nb1, nb2, gb1, gb2, Ppre, s);
    hipLaunchKernelGGL(fin_kernel, dim3(NB / 32), dim3(256), 0, stream,
                       Ppre, s, wT2, nb2, out);
}